// Round 11
// baseline (78.043 us; speedup 1.0000x reference)
//
#include <hip/hip_runtime.h>
#include <math.h>
#include <limits.h>

#define LL 2048
#define PP (LL*3)
#define FPB 8
#define NP 8
#define NBLK ((PP/(256*NP)) * ((3*LL)/FPB))   // 3 * 768 = 2304

// -------- device-global scratch (rewritten every call) --------
__device__ int   g_firstj[LL];
__device__ int   g_cnt[LL];
__device__ int   g_ii[LL];
__device__ int   g_jj[LL];
__device__ int   g_K;
__device__ int   g_done;
// folded frame records, 12 floats = 48 B: [M(9) | d(3)]; diff = p - M*t - d
// term0: frames [0, LL); term1: frames [LL, LL + LL + K)
__device__ __align__(16) float g_frames[(3*LL)*12];
// packed point records, 8 floats = 32 B: [p.xyz | t.xyz | pad pad]
__device__ __align__(16) float g_pts[PP*8];
__device__ double g_sum[2];

// rigid_from_3points for one residue: x = 9 floats (x1,x2,x3 rows)
__device__ inline void rigid3(const float* x, float* rot, float* tran) {
  float x1x=x[0],x1y=x[1],x1z=x[2];
  float x2x=x[3],x2y=x[4],x2z=x[5];
  float x3x=x[6],x3y=x[7],x3z=x[8];
  float v1x=x3x-x2x, v1y=x3y-x2y, v1z=x3z-x2z;
  float v2x=x1x-x2x, v2y=x1y-x2y, v2z=x1z-x2z;
  float n1 = sqrtf(v1x*v1x+v1y*v1y+v1z*v1z) + 0.001f;
  float e1x=v1x/n1, e1y=v1y/n1, e1z=v1z/n1;
  float dd = e1x*v2x+e1y*v2y+e1z*v2z;
  float u2x=v2x-e1x*dd, u2y=v2y-e1y*dd, u2z=v2z-e1z*dd;
  float n2 = sqrtf(u2x*u2x+u2y*u2y+u2z*u2z) + 1e-8f;
  float e2x=u2x/n2, e2y=u2y/n2, e2z=u2z/n2;
  rot[0]=e1x; rot[1]=e1y; rot[2]=e1z;
  rot[3]=e2x; rot[4]=e2y; rot[5]=e2z;
  rot[6]=e1y*e2z - e1z*e2y;
  rot[7]=e1z*e2x - e1x*e2z;
  rot[8]=e1x*e2y - e1y*e2x;
  tran[0]=x2x; tran[1]=x2y; tran[2]=x2z;
}

// folded record: M = A^T * B, d = tp - M*tt   (A=R_pred rows, B=R_true rows)
__device__ inline void packfr12(float* fr, const float* A, const float* tp,
                                const float* B, const float* tt) {
  float M[9];
  #pragma unroll
  for (int i = 0; i < 3; ++i)
    #pragma unroll
    for (int j = 0; j < 3; ++j)
      M[i*3+j] = A[0+i]*B[0+j] + A[3+i]*B[3+j] + A[6+i]*B[6+j];
  #pragma unroll
  for (int i = 0; i < 9; ++i) fr[i] = M[i];
  #pragma unroll
  for (int i = 0; i < 3; ++i)
    fr[9+i] = tp[i] - (M[i*3]*tt[0] + M[i*3+1]*tt[1] + M[i*3+2]*tt[2]);
}

// blocks [0,LL): per-row matrix scan (first j>i with m!=0)
// blocks [LL, LL+8): term0 folded frames
// blocks [LL+8, LL+8+24): packed point records
__global__ void __launch_bounds__(256) k_prep(const int4* __restrict__ m4,
                                              const float* __restrict__ coor,
                                              const float* __restrict__ target,
                                              const float* __restrict__ prot,
                                              const float* __restrict__ ptran) {
  int bid = blockIdx.x;
  int t = threadIdx.x;
  if (bid < LL) {
    int i = bid;                        // row
    const int4* row = m4 + (size_t)i*512;   // 2048 cols = 512 int4
    int4 a = row[2*t], b = row[2*t+1];
    int j0 = t*8;
    int best = INT_MAX;
    if (a.x && (j0   > i)) best = j0;
    if (a.y && (j0+1 > i)) best = min(best, j0+1);
    if (a.z && (j0+2 > i)) best = min(best, j0+2);
    if (a.w && (j0+3 > i)) best = min(best, j0+3);
    if (b.x && (j0+4 > i)) best = min(best, j0+4);
    if (b.y && (j0+5 > i)) best = min(best, j0+5);
    if (b.z && (j0+6 > i)) best = min(best, j0+6);
    if (b.w && (j0+7 > i)) best = min(best, j0+7);
    for (int o = 32; o >= 1; o >>= 1) best = min(best, __shfl_xor(best, o));
    __shared__ int wmin[4];
    int lane = t & 63, wid = t >> 6;
    if (lane == 0) wmin[wid] = best;
    __syncthreads();
    if (t == 0)
      g_firstj[i] = min(min(wmin[0], wmin[1]), min(wmin[2], wmin[3]));
  } else if (bid < LL + 8) {
    int f = (bid - LL)*256 + t;
    if (f == 0) { g_sum[0] = 0.0; g_sum[1] = 0.0; g_done = 0; }
    if (f >= LL) return;
    float B[9], tt[3];
    rigid3(target + f*9, B, tt);
    float A[9], tp[3];
    #pragma unroll
    for (int i = 0; i < 9; ++i) A[i] = prot[f*9+i];
    #pragma unroll
    for (int i = 0; i < 3; ++i) tp[i] = ptran[f*3+i];
    packfr12(g_frames + f*12, A, tp, B, tt);
  } else {
    int p = (bid - LL - 8)*256 + t;     // p < 6144
    float4* o4 = reinterpret_cast<float4*>(g_pts);
    o4[p*2+0] = make_float4(coor[p*3], coor[p*3+1], coor[p*3+2], target[p*3]);
    o4[p*2+1] = make_float4(target[p*3+1], target[p*3+2], 0.f, 0.f);
  }
}

// single block: exclusive prefix-sum of "row has pair", build ii/jj, K
__global__ void __launch_bounds__(1024) k_scan() {
  int t = threadIdx.x;
  int r0 = 2*t, r1 = 2*t+1;
  int f0 = g_firstj[r0], f1 = g_firstj[r1];
  int h0 = (f0 != INT_MAX) ? 1 : 0;
  int h1 = (f1 != INT_MAX) ? 1 : 0;
  int local = h0 + h1;
  int lane = t & 63;
  int wid  = t >> 6;                 // 16 waves
  int incl = local;
  for (int o = 1; o < 64; o <<= 1) {
    int v = __shfl_up(incl, o);
    if (lane >= o) incl += v;
  }
  __shared__ int wsum[16];
  if (lane == 63) wsum[wid] = incl;
  __syncthreads();
  if (t < 16) {
    int iv = wsum[t];
    for (int o = 1; o < 16; o <<= 1) {
      int u = __shfl_up(iv, o);
      if (t >= o) iv += u;
    }
    wsum[t] = iv;
  }
  __syncthreads();
  int waveoff = (wid == 0) ? 0 : wsum[wid-1];
  int excl = waveoff + incl - local;   // pairs among rows < r0
  g_cnt[r0] = excl;
  g_cnt[r1] = excl + h0;
  if (h0) { g_ii[excl]      = r0; g_jj[excl]      = f0; }
  if (h1) { g_ii[excl + h0] = r1; g_jj[excl + h0] = f1; }
  if (t == 1023) g_K = waveoff + incl;
}

// term1 folded frame records computed directly from coords (no aug buffers)
__global__ void k_augfr(const float* __restrict__ coor,
                        const float* __restrict__ target) {
  int idx = blockIdx.x*blockDim.x + threadIdx.x;
  float xp[9], xt[9];
  int pos;
  if (idx < LL) {
    pos = idx + g_cnt[idx];
    #pragma unroll
    for (int c = 0; c < 9; ++c) { xp[c] = coor[idx*9+c]; xt[c] = target[idx*9+c]; }
  } else {
    int k = idx - LL;
    if (k >= g_K) return;
    int a = g_ii[k], b = g_jj[k];
    pos = a + k + 1;
    #pragma unroll
    for (int c = 0; c < 9; ++c) {
      xp[c] = 0.5f*(coor[a*9+c]   + coor[b*9+c]);
      xt[c] = 0.5f*(target[a*9+c] + target[b*9+c]);
    }
  }
  float A[9], tp[3], B[9], tt[3];
  rigid3(xp, A, tp);
  rigid3(xt, B, tt);
  packfr12(g_frames + (size_t)(LL + pos)*12, A, tp, B, tt);
}

// fused FAPE: FPB=8 frames batch-loaded into registers/SGPRs BEFORE the loop
// (one wait per block, not per iteration — R7-R10 lesson), q fully unrolled:
// loop body is pure VALU. NP=8 points/thread. 1728 active blocks.
// FPB divides LL so a block never straddles the term0/term1 boundary.
// Last block to finish writes the final scalar.
__global__ void __launch_bounds__(256) k_fape(float* __restrict__ out) {
  int Ftot = 2*LL + g_K;
  int f0 = blockIdx.y * FPB;
  int t = threadIdx.x;

  if (f0 < Ftot) {
    int term1 = (f0 >= LL) ? 1 : 0;
    float clampv = term1 ? 5.f : 40.f;

    // batched wave-uniform frame load: 24 x float4, single wait, then pure VALU
    const float4* fr4 = reinterpret_cast<const float4*>(g_frames) + (size_t)f0*3;
    float4 fr[FPB*3];
    #pragma unroll
    for (int i = 0; i < FPB*3; ++i) fr[i] = fr4[i];

    int pbase = blockIdx.x*(256*NP) + t;   // grid.x * 256 * NP == PP exactly
    const float4* pt4 = reinterpret_cast<const float4*>(g_pts);
    float px[NP], py[NP], pz[NP], ttx[NP], tty[NP], ttz[NP];
    #pragma unroll
    for (int k = 0; k < NP; ++k) {
      int p = pbase + k*256;
      float4 a = pt4[p*2+0];
      float4 b = pt4[p*2+1];
      px[k] = a.x; py[k] = a.y; pz[k] = a.z;
      ttx[k] = a.w; tty[k] = b.x; ttz[k] = b.y;
    }
    float acc = 0.f;

    #pragma unroll
    for (int q = 0; q < FPB; ++q) {
      if (f0 + q < Ftot) {               // wave-uniform guard (tail K frames)
        float4 w0 = fr[q*3+0];   // M00 M01 M02 M10
        float4 w1 = fr[q*3+1];   // M11 M12 M20 M21
        float4 w2 = fr[q*3+2];   // M22 d0  d1  d2
        #pragma unroll
        for (int k = 0; k < NP; ++k) {
          float m0 = fmaf(w0.x, ttx[k], fmaf(w0.y, tty[k], fmaf(w0.z, ttz[k], w2.y)));
          float m1 = fmaf(w0.w, ttx[k], fmaf(w1.x, tty[k], fmaf(w1.y, ttz[k], w2.z)));
          float m2 = fmaf(w1.z, ttx[k], fmaf(w1.w, tty[k], fmaf(w2.x, ttz[k], w2.w)));
          float dx = px[k] - m0, dy = py[k] - m1, dz = pz[k] - m2;
          float ss = fmaf(dx, dx, fmaf(dy, dy, fmaf(dz, dz, 0.001f)));
          acc += fminf(__builtin_amdgcn_sqrtf(ss), clampv);
        }
      }
    }

    for (int o = 32; o >= 1; o >>= 1) acc += __shfl_down(acc, o);
    __shared__ float w[4];
    int lane = t & 63, wid = t >> 6;
    if (lane == 0) w[wid] = acc;
    __syncthreads();
    if (t == 0) {
      double s = (double)w[0] + (double)w[1] + (double)w[2] + (double)w[3];
      atomicAdd(&g_sum[term1], s);
    }
  }

  // ---- fused finalize: last block computes the output scalar ----
  if (t == 0) {
    __threadfence();
    int prev = atomicAdd(&g_done, 1);
    if (prev == NBLK - 1) {
      int K = g_K;
      double s0 = atomicAdd(&g_sum[0], 0.0);   // coherent reads
      double s1 = atomicAdd(&g_sum[1], 0.0);
      double fape = s0 / ((double)LL * (double)PP);
      double r;
      if (K == 0) r = fape / 10.0;
      else        r = (fape + s1 / ((double)(LL + K) * (double)PP)) / 10.0;
      out[0] = (float)r;
    }
  }
}

extern "C" void kernel_launch(void* const* d_in, const int* in_sizes, int n_in,
                              void* d_out, int out_size, void* d_ws, size_t ws_size,
                              hipStream_t stream) {
  const float* coor   = (const float*)d_in[0];
  const float* prot   = (const float*)d_in[1];
  const float* ptran  = (const float*)d_in[2];
  const float* target = (const float*)d_in[3];
  const int*   matrix = (const int*)d_in[4];
  float* out = (float*)d_out;

  k_prep<<<LL + 8 + PP/256, 256, 0, stream>>>((const int4*)matrix, coor, target, prot, ptran);
  k_scan<<<1, 1024, 0, stream>>>();
  k_augfr<<<16, 256, 0, stream>>>(coor, target);
  dim3 grid(PP/(256*NP), (3*LL)/FPB);   // 3 x 768 = 2304 blocks (1728 active)
  k_fape<<<grid, 256, 0, stream>>>(out);
}

// Round 12
// 47.041 us; speedup vs baseline: 1.6590x; 1.6590x over previous
//
#include <hip/hip_runtime.h>
#include <math.h>
#include <limits.h>

#define LL 2048
#define PP (LL*3)
#define PCHUNK 96                      // points per x-block
#define NXB (PP/PCHUNK)                // 64
#define NYB 24                         // frame blocks of 256 (max Ftot 6144)
#define NBLK (NXB*NYB)                 // 1536

typedef float f16v __attribute__((ext_vector_type(16)));

// -------- device-global scratch (rewritten every call) --------
__device__ int   g_firstj[LL];
__device__ int   g_cnt[LL];
__device__ int   g_ii[LL];
__device__ int   g_jj[LL];
__device__ int   g_K;
__device__ int   g_done;
// folded frame records, 12 floats = 48 B: [M(9) | d(3)]; diff = p - M*t - d
// term0: frames [0, LL); term1: frames [LL, LL + LL + K)
__device__ __align__(16) float g_frames[(3*LL)*12];
// tight point records, 6 floats = 24 B: [p.xyz | t.xyz]; 8-point group = 192 B
__device__ __align__(256) float g_pts[PP*6];
__device__ double g_sum[2];

// rigid_from_3points for one residue: x = 9 floats (x1,x2,x3 rows)
__device__ inline void rigid3(const float* x, float* rot, float* tran) {
  float x1x=x[0],x1y=x[1],x1z=x[2];
  float x2x=x[3],x2y=x[4],x2z=x[5];
  float x3x=x[6],x3y=x[7],x3z=x[8];
  float v1x=x3x-x2x, v1y=x3y-x2y, v1z=x3z-x2z;
  float v2x=x1x-x2x, v2y=x1y-x2y, v2z=x1z-x2z;
  float n1 = sqrtf(v1x*v1x+v1y*v1y+v1z*v1z) + 0.001f;
  float e1x=v1x/n1, e1y=v1y/n1, e1z=v1z/n1;
  float dd = e1x*v2x+e1y*v2y+e1z*v2z;
  float u2x=v2x-e1x*dd, u2y=v2y-e1y*dd, u2z=v2z-e1z*dd;
  float n2 = sqrtf(u2x*u2x+u2y*u2y+u2z*u2z) + 1e-8f;
  float e2x=u2x/n2, e2y=u2y/n2, e2z=u2z/n2;
  rot[0]=e1x; rot[1]=e1y; rot[2]=e1z;
  rot[3]=e2x; rot[4]=e2y; rot[5]=e2z;
  rot[6]=e1y*e2z - e1z*e2y;
  rot[7]=e1z*e2x - e1x*e2z;
  rot[8]=e1x*e2y - e1y*e2x;
  tran[0]=x2x; tran[1]=x2y; tran[2]=x2z;
}

// folded record: M = A^T * B, d = tp - M*tt   (A=R_pred rows, B=R_true rows)
__device__ inline void packfr12(float* fr, const float* A, const float* tp,
                                const float* B, const float* tt) {
  float M[9];
  #pragma unroll
  for (int i = 0; i < 3; ++i)
    #pragma unroll
    for (int j = 0; j < 3; ++j)
      M[i*3+j] = A[0+i]*B[0+j] + A[3+i]*B[3+j] + A[6+i]*B[6+j];
  #pragma unroll
  for (int i = 0; i < 9; ++i) fr[i] = M[i];
  #pragma unroll
  for (int i = 0; i < 3; ++i)
    fr[9+i] = tp[i] - (M[i*3]*tt[0] + M[i*3+1]*tt[1] + M[i*3+2]*tt[2]);
}

// blocks [0,LL): per-row matrix scan (first j>i with m!=0)
// blocks [LL, LL+8): term0 folded frames
// blocks [LL+8, LL+8+24): tight point records
__global__ void __launch_bounds__(256) k_prep(const int4* __restrict__ m4,
                                              const float* __restrict__ coor,
                                              const float* __restrict__ target,
                                              const float* __restrict__ prot,
                                              const float* __restrict__ ptran) {
  int bid = blockIdx.x;
  int t = threadIdx.x;
  if (bid < LL) {
    int i = bid;                        // row
    const int4* row = m4 + (size_t)i*512;   // 2048 cols = 512 int4
    int4 a = row[2*t], b = row[2*t+1];
    int j0 = t*8;
    int best = INT_MAX;
    if (a.x && (j0   > i)) best = j0;
    if (a.y && (j0+1 > i)) best = min(best, j0+1);
    if (a.z && (j0+2 > i)) best = min(best, j0+2);
    if (a.w && (j0+3 > i)) best = min(best, j0+3);
    if (b.x && (j0+4 > i)) best = min(best, j0+4);
    if (b.y && (j0+5 > i)) best = min(best, j0+5);
    if (b.z && (j0+6 > i)) best = min(best, j0+6);
    if (b.w && (j0+7 > i)) best = min(best, j0+7);
    for (int o = 32; o >= 1; o >>= 1) best = min(best, __shfl_xor(best, o));
    __shared__ int wmin[4];
    int lane = t & 63, wid = t >> 6;
    if (lane == 0) wmin[wid] = best;
    __syncthreads();
    if (t == 0)
      g_firstj[i] = min(min(wmin[0], wmin[1]), min(wmin[2], wmin[3]));
  } else if (bid < LL + 8) {
    int f = (bid - LL)*256 + t;
    if (f == 0) { g_sum[0] = 0.0; g_sum[1] = 0.0; g_done = 0; }
    if (f >= LL) return;
    float B[9], tt[3];
    rigid3(target + f*9, B, tt);
    float A[9], tp[3];
    #pragma unroll
    for (int i = 0; i < 9; ++i) A[i] = prot[f*9+i];
    #pragma unroll
    for (int i = 0; i < 3; ++i) tp[i] = ptran[f*3+i];
    packfr12(g_frames + f*12, A, tp, B, tt);
  } else {
    int p = (bid - LL - 8)*256 + t;     // p < 6144
    g_pts[p*6+0] = coor[p*3];
    g_pts[p*6+1] = coor[p*3+1];
    g_pts[p*6+2] = coor[p*3+2];
    g_pts[p*6+3] = target[p*3];
    g_pts[p*6+4] = target[p*3+1];
    g_pts[p*6+5] = target[p*3+2];
  }
}

// single block: exclusive prefix-sum of "row has pair", build ii/jj, K
__global__ void __launch_bounds__(1024) k_scan() {
  int t = threadIdx.x;
  int r0 = 2*t, r1 = 2*t+1;
  int f0 = g_firstj[r0], f1 = g_firstj[r1];
  int h0 = (f0 != INT_MAX) ? 1 : 0;
  int h1 = (f1 != INT_MAX) ? 1 : 0;
  int local = h0 + h1;
  int lane = t & 63;
  int wid  = t >> 6;                 // 16 waves
  int incl = local;
  for (int o = 1; o < 64; o <<= 1) {
    int v = __shfl_up(incl, o);
    if (lane >= o) incl += v;
  }
  __shared__ int wsum[16];
  if (lane == 63) wsum[wid] = incl;
  __syncthreads();
  if (t < 16) {
    int iv = wsum[t];
    for (int o = 1; o < 16; o <<= 1) {
      int u = __shfl_up(iv, o);
      if (t >= o) iv += u;
    }
    wsum[t] = iv;
  }
  __syncthreads();
  int waveoff = (wid == 0) ? 0 : wsum[wid-1];
  int excl = waveoff + incl - local;   // pairs among rows < r0
  g_cnt[r0] = excl;
  g_cnt[r1] = excl + h0;
  if (h0) { g_ii[excl]      = r0; g_jj[excl]      = f0; }
  if (h1) { g_ii[excl + h0] = r1; g_jj[excl + h0] = f1; }
  if (t == 1023) g_K = waveoff + incl;
}

// term1 folded frame records computed directly from coords (no aug buffers)
__global__ void k_augfr(const float* __restrict__ coor,
                        const float* __restrict__ target) {
  int idx = blockIdx.x*blockDim.x + threadIdx.x;
  float xp[9], xt[9];
  int pos;
  if (idx < LL) {
    pos = idx + g_cnt[idx];
    #pragma unroll
    for (int c = 0; c < 9; ++c) { xp[c] = coor[idx*9+c]; xt[c] = target[idx*9+c]; }
  } else {
    int k = idx - LL;
    if (k >= g_K) return;
    int a = g_ii[k], b = g_jj[k];
    pos = a + k + 1;
    #pragma unroll
    for (int c = 0; c < 9; ++c) {
      xp[c] = 0.5f*(coor[a*9+c]   + coor[b*9+c]);
      xt[c] = 0.5f*(target[a*9+c] + target[b*9+c]);
    }
  }
  float A[9], tp[3], B[9], tt[3];
  rigid3(xp, A, tp);
  rigid3(xt, B, tt);
  packfr12(g_frames + (size_t)(LL + pos)*12, A, tp, B, tt);
}

// TRANSPOSED fused FAPE: each thread owns ONE frame (12 floats in VGPRs,
// loaded once); points stream as wave-uniform 8-point batches via named
// ext_vector loads (-> s_load_dwordx16, SGPRs; named scalars, NOT arrays —
// R11 lesson). Inner loop is pure VALU with 1 SGPR operand per FMA.
// y-blocks of 256 frames: term boundary at 2048 is block-aligned.
__global__ void __launch_bounds__(256) k_fape(float* __restrict__ out) {
  int Ftot = 2*LL + g_K;
  int t = threadIdx.x;
  int f = blockIdx.y*256 + t;
  int term1 = (blockIdx.y >= 8) ? 1 : 0;
  float clampv = term1 ? 5.f : 40.f;
  bool act = (f < Ftot);

  // per-thread frame into registers (12 floats); inactive -> frame 0 (finite)
  int fidx = act ? f : 0;
  const float4* fr4 = reinterpret_cast<const float4*>(g_frames) + (size_t)fidx*3;
  float4 A0 = fr4[0];   // M00 M01 M02 M10
  float4 A1 = fr4[1];   // M11 M12 M20 M21
  float4 A2 = fr4[2];   // M22 d0  d1  d2

  float acc = 0.f;
  int p0 = blockIdx.x * PCHUNK;

  #pragma unroll 1
  for (int pc = 0; pc < PCHUNK; pc += 8) {
    // 8 points = 48 floats = 3 x s_load_dwordx16 (wave-uniform, named)
    const f16v* u = reinterpret_cast<const f16v*>(g_pts + (size_t)(p0 + pc)*6);
    f16v b0 = u[0], b1 = u[1], b2 = u[2];
    #pragma unroll
    for (int j = 0; j < 8; ++j) {
      // flat index of point j: floats [j*6 .. j*6+5] across b0,b1,b2
      #define PTF(c) ((j*6+(c)) < 16 ? b0[(j*6+(c))&15] : ((j*6+(c)) < 32 ? b1[(j*6+(c))&15] : b2[(j*6+(c))&15]))
      float px = PTF(0), py = PTF(1), pz = PTF(2);
      float tx = PTF(3), ty = PTF(4), tz = PTF(5);
      #undef PTF
      float m0 = fmaf(A0.x, tx, fmaf(A0.y, ty, fmaf(A0.z, tz, A2.y)));
      float m1 = fmaf(A0.w, tx, fmaf(A1.x, ty, fmaf(A1.y, tz, A2.z)));
      float m2 = fmaf(A1.z, tx, fmaf(A1.w, ty, fmaf(A2.x, tz, A2.w)));
      float dx = px - m0, dy = py - m1, dz = pz - m2;
      float ss = fmaf(dx, dx, fmaf(dy, dy, fmaf(dz, dz, 0.001f)));
      acc += fminf(__builtin_amdgcn_sqrtf(ss), clampv);
    }
  }

  acc = act ? acc : 0.f;
  for (int o = 32; o >= 1; o >>= 1) acc += __shfl_down(acc, o);
  __shared__ float w[4];
  int lane = t & 63, wid = t >> 6;
  if (lane == 0) w[wid] = acc;
  __syncthreads();
  if (t == 0) {
    double s = (double)w[0] + (double)w[1] + (double)w[2] + (double)w[3];
    if (s != 0.0) atomicAdd(&g_sum[term1], s);
    // ---- fused finalize: last block computes the output scalar ----
    __threadfence();
    int prev = atomicAdd(&g_done, 1);
    if (prev == NBLK - 1) {
      int K = g_K;
      double s0 = atomicAdd(&g_sum[0], 0.0);   // coherent reads
      double s1 = atomicAdd(&g_sum[1], 0.0);
      double fape = s0 / ((double)LL * (double)PP);
      double r;
      if (K == 0) r = fape / 10.0;
      else        r = (fape + s1 / ((double)(LL + K) * (double)PP)) / 10.0;
      out[0] = (float)r;
    }
  }
}

extern "C" void kernel_launch(void* const* d_in, const int* in_sizes, int n_in,
                              void* d_out, int out_size, void* d_ws, size_t ws_size,
                              hipStream_t stream) {
  const float* coor   = (const float*)d_in[0];
  const float* prot   = (const float*)d_in[1];
  const float* ptran  = (const float*)d_in[2];
  const float* target = (const float*)d_in[3];
  const int*   matrix = (const int*)d_in[4];
  float* out = (float*)d_out;

  k_prep<<<LL + 8 + PP/256, 256, 0, stream>>>((const int4*)matrix, coor, target, prot, ptran);
  k_scan<<<1, 1024, 0, stream>>>();
  k_augfr<<<16, 256, 0, stream>>>(coor, target);
  dim3 grid(NXB, NYB);                 // 64 x 24 = 1536 blocks
  k_fape<<<grid, 256, 0, stream>>>(out);
}

// Round 13
// 44.758 us; speedup vs baseline: 1.7437x; 1.0510x over previous
//
#include <hip/hip_runtime.h>
#include <math.h>
#include <limits.h>

#define LL 2048
#define PP (LL*3)
#define FPB 16
#define NP 8
#define NBLK ((PP/(256*NP)) * ((3*LL)/FPB))   // 3 * 384 = 1152

// -------- device-global scratch (rewritten every call) --------
__device__ int   g_firstj[LL];
__device__ int   g_cnt[LL];
__device__ int   g_ii[LL];
__device__ int   g_jj[LL];
__device__ int   g_K;
__device__ int   g_done;
// folded frame records, 12 floats = 48 B: [M(9) | d(3)]; diff = p - M*t - d
// term0: frames [0, LL); term1: frames [LL, LL + LL + K)
__device__ __align__(16) float g_frames[(3*LL)*12];
// packed point records, 8 floats = 32 B: [p.xyz | t.xyz | pad pad]
__device__ __align__(16) float g_pts[PP*8];
__device__ double g_sum[2];

// rigid_from_3points for one residue: x = 9 floats (x1,x2,x3 rows)
__device__ inline void rigid3(const float* x, float* rot, float* tran) {
  float x1x=x[0],x1y=x[1],x1z=x[2];
  float x2x=x[3],x2y=x[4],x2z=x[5];
  float x3x=x[6],x3y=x[7],x3z=x[8];
  float v1x=x3x-x2x, v1y=x3y-x2y, v1z=x3z-x2z;
  float v2x=x1x-x2x, v2y=x1y-x2y, v2z=x1z-x2z;
  float n1 = sqrtf(v1x*v1x+v1y*v1y+v1z*v1z) + 0.001f;
  float e1x=v1x/n1, e1y=v1y/n1, e1z=v1z/n1;
  float dd = e1x*v2x+e1y*v2y+e1z*v2z;
  float u2x=v2x-e1x*dd, u2y=v2y-e1y*dd, u2z=v2z-e1z*dd;
  float n2 = sqrtf(u2x*u2x+u2y*u2y+u2z*u2z) + 1e-8f;
  float e2x=u2x/n2, e2y=u2y/n2, e2z=u2z/n2;
  rot[0]=e1x; rot[1]=e1y; rot[2]=e1z;
  rot[3]=e2x; rot[4]=e2y; rot[5]=e2z;
  rot[6]=e1y*e2z - e1z*e2y;
  rot[7]=e1z*e2x - e1x*e2z;
  rot[8]=e1x*e2y - e1y*e2x;
  tran[0]=x2x; tran[1]=x2y; tran[2]=x2z;
}

// folded record: M = A^T * B, d = tp - M*tt   (A=R_pred rows, B=R_true rows)
__device__ inline void packfr12(float* fr, const float* A, const float* tp,
                                const float* B, const float* tt) {
  float M[9];
  #pragma unroll
  for (int i = 0; i < 3; ++i)
    #pragma unroll
    for (int j = 0; j < 3; ++j)
      M[i*3+j] = A[0+i]*B[0+j] + A[3+i]*B[3+j] + A[6+i]*B[6+j];
  #pragma unroll
  for (int i = 0; i < 9; ++i) fr[i] = M[i];
  #pragma unroll
  for (int i = 0; i < 3; ++i)
    fr[9+i] = tp[i] - (M[i*3]*tt[0] + M[i*3+1]*tt[1] + M[i*3+2]*tt[2]);
}

// blocks [0,LL): per-row matrix scan (first j>i with m!=0)
// blocks [LL, LL+8): term0 folded frames
// blocks [LL+8, LL+8+24): packed point records
__global__ void __launch_bounds__(256) k_prep(const int4* __restrict__ m4,
                                              const float* __restrict__ coor,
                                              const float* __restrict__ target,
                                              const float* __restrict__ prot,
                                              const float* __restrict__ ptran) {
  int bid = blockIdx.x;
  int t = threadIdx.x;
  if (bid < LL) {
    int i = bid;                        // row
    const int4* row = m4 + (size_t)i*512;   // 2048 cols = 512 int4
    int4 a = row[2*t], b = row[2*t+1];
    int j0 = t*8;
    int best = INT_MAX;
    if (a.x && (j0   > i)) best = j0;
    if (a.y && (j0+1 > i)) best = min(best, j0+1);
    if (a.z && (j0+2 > i)) best = min(best, j0+2);
    if (a.w && (j0+3 > i)) best = min(best, j0+3);
    if (b.x && (j0+4 > i)) best = min(best, j0+4);
    if (b.y && (j0+5 > i)) best = min(best, j0+5);
    if (b.z && (j0+6 > i)) best = min(best, j0+6);
    if (b.w && (j0+7 > i)) best = min(best, j0+7);
    for (int o = 32; o >= 1; o >>= 1) best = min(best, __shfl_xor(best, o));
    __shared__ int wmin[4];
    int lane = t & 63, wid = t >> 6;
    if (lane == 0) wmin[wid] = best;
    __syncthreads();
    if (t == 0)
      g_firstj[i] = min(min(wmin[0], wmin[1]), min(wmin[2], wmin[3]));
  } else if (bid < LL + 8) {
    int f = (bid - LL)*256 + t;
    if (f == 0) { g_sum[0] = 0.0; g_sum[1] = 0.0; g_done = 0; }
    if (f >= LL) return;
    float B[9], tt[3];
    rigid3(target + f*9, B, tt);
    float A[9], tp[3];
    #pragma unroll
    for (int i = 0; i < 9; ++i) A[i] = prot[f*9+i];
    #pragma unroll
    for (int i = 0; i < 3; ++i) tp[i] = ptran[f*3+i];
    packfr12(g_frames + f*12, A, tp, B, tt);
  } else {
    int p = (bid - LL - 8)*256 + t;     // p < 6144
    float4* o4 = reinterpret_cast<float4*>(g_pts);
    o4[p*2+0] = make_float4(coor[p*3], coor[p*3+1], coor[p*3+2], target[p*3]);
    o4[p*2+1] = make_float4(target[p*3+1], target[p*3+2], 0.f, 0.f);
  }
}

// single block: scan (prefix-sum of "row has pair", build ii/jj, K), then the
// same block computes all term1 folded frame records (fused k_augfr;
// __syncthreads fences the block's global writes so g_cnt/g_ii/g_jj/g_K are
// visible to the aug loop).
__global__ void __launch_bounds__(1024) k_scanaug(const float* __restrict__ coor,
                                                  const float* __restrict__ target) {
  int t = threadIdx.x;
  int r0 = 2*t, r1 = 2*t+1;
  int f0 = g_firstj[r0], f1 = g_firstj[r1];
  int h0 = (f0 != INT_MAX) ? 1 : 0;
  int h1 = (f1 != INT_MAX) ? 1 : 0;
  int local = h0 + h1;
  int lane = t & 63;
  int wid  = t >> 6;                 // 16 waves
  int incl = local;
  for (int o = 1; o < 64; o <<= 1) {
    int v = __shfl_up(incl, o);
    if (lane >= o) incl += v;
  }
  __shared__ int wsum[16];
  if (lane == 63) wsum[wid] = incl;
  __syncthreads();
  if (t < 16) {
    int iv = wsum[t];
    for (int o = 1; o < 16; o <<= 1) {
      int u = __shfl_up(iv, o);
      if (t >= o) iv += u;
    }
    wsum[t] = iv;
  }
  __syncthreads();
  int waveoff = (wid == 0) ? 0 : wsum[wid-1];
  int excl = waveoff + incl - local;   // pairs among rows < r0
  g_cnt[r0] = excl;
  g_cnt[r1] = excl + h0;
  if (h0) { g_ii[excl]      = r0; g_jj[excl]      = f0; }
  if (h1) { g_ii[excl + h0] = r1; g_jj[excl + h0] = f1; }
  if (t == 1023) g_K = waveoff + incl;
  __syncthreads();                     // fences global writes block-wide

  int K = g_K;
  for (int idx = t; idx < LL + K; idx += 1024) {
    float xp[9], xt[9];
    int pos;
    if (idx < LL) {
      pos = idx + g_cnt[idx];
      #pragma unroll
      for (int c = 0; c < 9; ++c) { xp[c] = coor[idx*9+c]; xt[c] = target[idx*9+c]; }
    } else {
      int k = idx - LL;
      int a = g_ii[k], b = g_jj[k];
      pos = a + k + 1;
      #pragma unroll
      for (int c = 0; c < 9; ++c) {
        xp[c] = 0.5f*(coor[a*9+c]   + coor[b*9+c]);
        xt[c] = 0.5f*(target[a*9+c] + target[b*9+c]);
      }
    }
    float A[9], tp[3], B[9], tt[3];
    rigid3(xp, A, tp);
    rigid3(xt, B, tt);
    packfr12(g_frames + (size_t)(LL + pos)*12, A, tp, B, tt);
  }
}

// fused FAPE (R7 structure, proven best): NP=8 points/thread in VGPRs,
// FPB=16 frames via wave-uniform global float4 loads (-> s_load, SGPRs).
// unroll 4: one lgkmcnt drain per 4 frames instead of per 2 (SMEM returns
// out-of-order, so each use forces a full drain — amortize it).
// FPB divides LL so a block never straddles the term0/term1 boundary.
// Last block to finish writes the final scalar.
__global__ void __launch_bounds__(256, 4) k_fape(float* __restrict__ out) {
  int Ftot = 2*LL + g_K;
  int f0 = blockIdx.y * FPB;
  int t = threadIdx.x;

  if (f0 < Ftot) {
    int nf = min(FPB, Ftot - f0);
    int term1 = (f0 >= LL) ? 1 : 0;
    float clampv = term1 ? 5.f : 40.f;

    int pbase = blockIdx.x*(256*NP) + t;   // grid.x * 256 * NP == PP exactly
    const float4* pt4 = reinterpret_cast<const float4*>(g_pts);
    float px[NP], py[NP], pz[NP], ttx[NP], tty[NP], ttz[NP];
    #pragma unroll
    for (int k = 0; k < NP; ++k) {
      int p = pbase + k*256;
      float4 a = pt4[p*2+0];
      float4 b = pt4[p*2+1];
      px[k] = a.x; py[k] = a.y; pz[k] = a.z;
      ttx[k] = a.w; tty[k] = b.x; ttz[k] = b.y;
    }
    float acc = 0.f;

    // wave-uniform frame pointer: compiler promotes to scalar loads (SGPRs)
    const float4* fr4 = reinterpret_cast<const float4*>(g_frames) + (size_t)f0*3;
    #pragma unroll 4
    for (int q = 0; q < nf; ++q) {
      float4 w0 = fr4[q*3+0];   // M00 M01 M02 M10
      float4 w1 = fr4[q*3+1];   // M11 M12 M20 M21
      float4 w2 = fr4[q*3+2];   // M22 d0  d1  d2
      #pragma unroll
      for (int k = 0; k < NP; ++k) {
        float m0 = fmaf(w0.x, ttx[k], fmaf(w0.y, tty[k], fmaf(w0.z, ttz[k], w2.y)));
        float m1 = fmaf(w0.w, ttx[k], fmaf(w1.x, tty[k], fmaf(w1.y, ttz[k], w2.z)));
        float m2 = fmaf(w1.z, ttx[k], fmaf(w1.w, tty[k], fmaf(w2.x, ttz[k], w2.w)));
        float dx = px[k] - m0, dy = py[k] - m1, dz = pz[k] - m2;
        float ss = fmaf(dx, dx, fmaf(dy, dy, fmaf(dz, dz, 0.001f)));
        acc += fminf(__builtin_amdgcn_sqrtf(ss), clampv);
      }
    }

    for (int o = 32; o >= 1; o >>= 1) acc += __shfl_down(acc, o);
    __shared__ float w[4];
    int lane = t & 63, wid = t >> 6;
    if (lane == 0) w[wid] = acc;
    __syncthreads();
    if (t == 0) {
      double s = (double)w[0] + (double)w[1] + (double)w[2] + (double)w[3];
      atomicAdd(&g_sum[term1], s);
    }
  }

  // ---- fused finalize: last block computes the output scalar ----
  if (t == 0) {
    __threadfence();
    int prev = atomicAdd(&g_done, 1);
    if (prev == NBLK - 1) {
      int K = g_K;
      double s0 = atomicAdd(&g_sum[0], 0.0);   // coherent reads
      double s1 = atomicAdd(&g_sum[1], 0.0);
      double fape = s0 / ((double)LL * (double)PP);
      double r;
      if (K == 0) r = fape / 10.0;
      else        r = (fape + s1 / ((double)(LL + K) * (double)PP)) / 10.0;
      out[0] = (float)r;
    }
  }
}

extern "C" void kernel_launch(void* const* d_in, const int* in_sizes, int n_in,
                              void* d_out, int out_size, void* d_ws, size_t ws_size,
                              hipStream_t stream) {
  const float* coor   = (const float*)d_in[0];
  const float* prot   = (const float*)d_in[1];
  const float* ptran  = (const float*)d_in[2];
  const float* target = (const float*)d_in[3];
  const int*   matrix = (const int*)d_in[4];
  float* out = (float*)d_out;

  k_prep<<<LL + 8 + PP/256, 256, 0, stream>>>((const int4*)matrix, coor, target, prot, ptran);
  k_scanaug<<<1, 1024, 0, stream>>>(coor, target);
  dim3 grid(PP/(256*NP), (3*LL)/FPB);   // 3 x 384 = 1152 blocks (864 active)
  k_fape<<<grid, 256, 0, stream>>>(out);
}

// Round 14
// 41.521 us; speedup vs baseline: 1.8796x; 1.0780x over previous
//
#include <hip/hip_runtime.h>
#include <math.h>
#include <limits.h>

#define LL 2048
#define PP (LL*3)
#define FPB 16
#define NP 8
#define NBLK ((PP/(256*NP)) * ((3*LL)/FPB))   // 3 * 384 = 1152

// -------- device-global scratch (rewritten every call) --------
__device__ int   g_firstj[LL];
__device__ int   g_cnt[LL];
__device__ int   g_ii[LL];
__device__ int   g_jj[LL];
__device__ int   g_K;
__device__ int   g_done;
// folded frame records, 12 floats = 48 B: [M(9) | d(3)]; diff = p - M*t - d
// term0: frames [0, LL); term1: frames [LL, LL + LL + K)
__device__ __align__(16) float g_frames[(3*LL)*12];
// packed point records, 8 floats = 32 B: [p.xyz | t.xyz | pad pad]
__device__ __align__(16) float g_pts[PP*8];
__device__ double g_sum[2];

// rigid_from_3points for one residue: x = 9 floats (x1,x2,x3 rows)
__device__ inline void rigid3(const float* x, float* rot, float* tran) {
  float x1x=x[0],x1y=x[1],x1z=x[2];
  float x2x=x[3],x2y=x[4],x2z=x[5];
  float x3x=x[6],x3y=x[7],x3z=x[8];
  float v1x=x3x-x2x, v1y=x3y-x2y, v1z=x3z-x2z;
  float v2x=x1x-x2x, v2y=x1y-x2y, v2z=x1z-x2z;
  float n1 = sqrtf(v1x*v1x+v1y*v1y+v1z*v1z) + 0.001f;
  float e1x=v1x/n1, e1y=v1y/n1, e1z=v1z/n1;
  float dd = e1x*v2x+e1y*v2y+e1z*v2z;
  float u2x=v2x-e1x*dd, u2y=v2y-e1y*dd, u2z=v2z-e1z*dd;
  float n2 = sqrtf(u2x*u2x+u2y*u2y+u2z*u2z) + 1e-8f;
  float e2x=u2x/n2, e2y=u2y/n2, e2z=u2z/n2;
  rot[0]=e1x; rot[1]=e1y; rot[2]=e1z;
  rot[3]=e2x; rot[4]=e2y; rot[5]=e2z;
  rot[6]=e1y*e2z - e1z*e2y;
  rot[7]=e1z*e2x - e1x*e2z;
  rot[8]=e1x*e2y - e1y*e2x;
  tran[0]=x2x; tran[1]=x2y; tran[2]=x2z;
}

// folded record: M = A^T * B, d = tp - M*tt   (A=R_pred rows, B=R_true rows)
__device__ inline void packfr12(float* fr, const float* A, const float* tp,
                                const float* B, const float* tt) {
  float M[9];
  #pragma unroll
  for (int i = 0; i < 3; ++i)
    #pragma unroll
    for (int j = 0; j < 3; ++j)
      M[i*3+j] = A[0+i]*B[0+j] + A[3+i]*B[3+j] + A[6+i]*B[6+j];
  #pragma unroll
  for (int i = 0; i < 9; ++i) fr[i] = M[i];
  #pragma unroll
  for (int i = 0; i < 3; ++i)
    fr[9+i] = tp[i] - (M[i*3]*tt[0] + M[i*3+1]*tt[1] + M[i*3+2]*tt[2]);
}

// blocks [0,LL): per-row matrix scan (first j>i with m!=0)
// blocks [LL, LL+8): term0 folded frames
// blocks [LL+8, LL+8+24): packed point records
__global__ void __launch_bounds__(256) k_prep(const int4* __restrict__ m4,
                                              const float* __restrict__ coor,
                                              const float* __restrict__ target,
                                              const float* __restrict__ prot,
                                              const float* __restrict__ ptran) {
  int bid = blockIdx.x;
  int t = threadIdx.x;
  if (bid < LL) {
    int i = bid;                        // row
    const int4* row = m4 + (size_t)i*512;   // 2048 cols = 512 int4
    int4 a = row[2*t], b = row[2*t+1];
    int j0 = t*8;
    int best = INT_MAX;
    if (a.x && (j0   > i)) best = j0;
    if (a.y && (j0+1 > i)) best = min(best, j0+1);
    if (a.z && (j0+2 > i)) best = min(best, j0+2);
    if (a.w && (j0+3 > i)) best = min(best, j0+3);
    if (b.x && (j0+4 > i)) best = min(best, j0+4);
    if (b.y && (j0+5 > i)) best = min(best, j0+5);
    if (b.z && (j0+6 > i)) best = min(best, j0+6);
    if (b.w && (j0+7 > i)) best = min(best, j0+7);
    for (int o = 32; o >= 1; o >>= 1) best = min(best, __shfl_xor(best, o));
    __shared__ int wmin[4];
    int lane = t & 63, wid = t >> 6;
    if (lane == 0) wmin[wid] = best;
    __syncthreads();
    if (t == 0)
      g_firstj[i] = min(min(wmin[0], wmin[1]), min(wmin[2], wmin[3]));
  } else if (bid < LL + 8) {
    int f = (bid - LL)*256 + t;
    if (f == 0) { g_sum[0] = 0.0; g_sum[1] = 0.0; g_done = 0; }
    if (f >= LL) return;
    float B[9], tt[3];
    rigid3(target + f*9, B, tt);
    float A[9], tp[3];
    #pragma unroll
    for (int i = 0; i < 9; ++i) A[i] = prot[f*9+i];
    #pragma unroll
    for (int i = 0; i < 3; ++i) tp[i] = ptran[f*3+i];
    packfr12(g_frames + f*12, A, tp, B, tt);
  } else {
    int p = (bid - LL - 8)*256 + t;     // p < 6144
    float4* o4 = reinterpret_cast<float4*>(g_pts);
    o4[p*2+0] = make_float4(coor[p*3], coor[p*3+1], coor[p*3+2], target[p*3]);
    o4[p*2+1] = make_float4(target[p*3+1], target[p*3+2], 0.f, 0.f);
  }
}

// single block: exclusive prefix-sum of "row has pair", build ii/jj, K
__global__ void __launch_bounds__(1024) k_scan() {
  int t = threadIdx.x;
  int r0 = 2*t, r1 = 2*t+1;
  int f0 = g_firstj[r0], f1 = g_firstj[r1];
  int h0 = (f0 != INT_MAX) ? 1 : 0;
  int h1 = (f1 != INT_MAX) ? 1 : 0;
  int local = h0 + h1;
  int lane = t & 63;
  int wid  = t >> 6;                 // 16 waves
  int incl = local;
  for (int o = 1; o < 64; o <<= 1) {
    int v = __shfl_up(incl, o);
    if (lane >= o) incl += v;
  }
  __shared__ int wsum[16];
  if (lane == 63) wsum[wid] = incl;
  __syncthreads();
  if (t < 16) {
    int iv = wsum[t];
    for (int o = 1; o < 16; o <<= 1) {
      int u = __shfl_up(iv, o);
      if (t >= o) iv += u;
    }
    wsum[t] = iv;
  }
  __syncthreads();
  int waveoff = (wid == 0) ? 0 : wsum[wid-1];
  int excl = waveoff + incl - local;   // pairs among rows < r0
  g_cnt[r0] = excl;
  g_cnt[r1] = excl + h0;
  if (h0) { g_ii[excl]      = r0; g_jj[excl]      = f0; }
  if (h1) { g_ii[excl + h0] = r1; g_jj[excl + h0] = f1; }
  if (t == 1023) g_K = waveoff + incl;
}

// term1 folded frame records computed directly from coords (no aug buffers)
__global__ void k_augfr(const float* __restrict__ coor,
                        const float* __restrict__ target) {
  int idx = blockIdx.x*blockDim.x + threadIdx.x;
  float xp[9], xt[9];
  int pos;
  if (idx < LL) {
    pos = idx + g_cnt[idx];
    #pragma unroll
    for (int c = 0; c < 9; ++c) { xp[c] = coor[idx*9+c]; xt[c] = target[idx*9+c]; }
  } else {
    int k = idx - LL;
    if (k >= g_K) return;
    int a = g_ii[k], b = g_jj[k];
    pos = a + k + 1;
    #pragma unroll
    for (int c = 0; c < 9; ++c) {
      xp[c] = 0.5f*(coor[a*9+c]   + coor[b*9+c]);
      xt[c] = 0.5f*(target[a*9+c] + target[b*9+c]);
    }
  }
  float A[9], tp[3], B[9], tt[3];
  rigid3(xp, A, tp);
  rigid3(xt, B, tt);
  packfr12(g_frames + (size_t)(LL + pos)*12, A, tp, B, tt);
}

// fused FAPE — EXACT R7 structure (measured best: ~25 us): NP=8 points/thread
// in VGPRs (live set just under 64), FPB=16 frames via wave-uniform global
// float4 loads (-> s_load, SGPRs), #pragma unroll 2, launch_bounds(256,4).
// FPB divides LL so a block never straddles the term0/term1 boundary.
// Only delta vs R7: last finished block writes the final scalar (saves the
// k_final launch; proven neutral in R10).
__global__ void __launch_bounds__(256, 4) k_fape(float* __restrict__ out) {
  int Ftot = 2*LL + g_K;
  int f0 = blockIdx.y * FPB;
  int t = threadIdx.x;

  if (f0 < Ftot) {
    int nf = min(FPB, Ftot - f0);
    int term1 = (f0 >= LL) ? 1 : 0;
    float clampv = term1 ? 5.f : 40.f;

    int pbase = blockIdx.x*(256*NP) + t;   // grid.x * 256 * NP == PP exactly
    const float4* pt4 = reinterpret_cast<const float4*>(g_pts);
    float px[NP], py[NP], pz[NP], ttx[NP], tty[NP], ttz[NP];
    #pragma unroll
    for (int k = 0; k < NP; ++k) {
      int p = pbase + k*256;
      float4 a = pt4[p*2+0];
      float4 b = pt4[p*2+1];
      px[k] = a.x; py[k] = a.y; pz[k] = a.z;
      ttx[k] = a.w; tty[k] = b.x; ttz[k] = b.y;
    }
    float acc = 0.f;

    // wave-uniform frame pointer: compiler promotes to scalar loads (SGPRs)
    const float4* fr4 = reinterpret_cast<const float4*>(g_frames) + (size_t)f0*3;
    #pragma unroll 2
    for (int q = 0; q < nf; ++q) {
      float4 w0 = fr4[q*3+0];   // M00 M01 M02 M10
      float4 w1 = fr4[q*3+1];   // M11 M12 M20 M21
      float4 w2 = fr4[q*3+2];   // M22 d0  d1  d2
      #pragma unroll
      for (int k = 0; k < NP; ++k) {
        float m0 = fmaf(w0.x, ttx[k], fmaf(w0.y, tty[k], fmaf(w0.z, ttz[k], w2.y)));
        float m1 = fmaf(w0.w, ttx[k], fmaf(w1.x, tty[k], fmaf(w1.y, ttz[k], w2.z)));
        float m2 = fmaf(w1.z, ttx[k], fmaf(w1.w, tty[k], fmaf(w2.x, ttz[k], w2.w)));
        float dx = px[k] - m0, dy = py[k] - m1, dz = pz[k] - m2;
        float ss = fmaf(dx, dx, fmaf(dy, dy, fmaf(dz, dz, 0.001f)));
        acc += fminf(__builtin_amdgcn_sqrtf(ss), clampv);
      }
    }

    for (int o = 32; o >= 1; o >>= 1) acc += __shfl_down(acc, o);
    __shared__ float w[4];
    int lane = t & 63, wid = t >> 6;
    if (lane == 0) w[wid] = acc;
    __syncthreads();
    if (t == 0) {
      double s = (double)w[0] + (double)w[1] + (double)w[2] + (double)w[3];
      atomicAdd(&g_sum[term1], s);
    }
  }

  // ---- fused finalize: last block computes the output scalar ----
  if (t == 0) {
    __threadfence();
    int prev = atomicAdd(&g_done, 1);
    if (prev == NBLK - 1) {
      int K = g_K;
      double s0 = atomicAdd(&g_sum[0], 0.0);   // coherent reads
      double s1 = atomicAdd(&g_sum[1], 0.0);
      double fape = s0 / ((double)LL * (double)PP);
      double r;
      if (K == 0) r = fape / 10.0;
      else        r = (fape + s1 / ((double)(LL + K) * (double)PP)) / 10.0;
      out[0] = (float)r;
    }
  }
}

extern "C" void kernel_launch(void* const* d_in, const int* in_sizes, int n_in,
                              void* d_out, int out_size, void* d_ws, size_t ws_size,
                              hipStream_t stream) {
  const float* coor   = (const float*)d_in[0];
  const float* prot   = (const float*)d_in[1];
  const float* ptran  = (const float*)d_in[2];
  const float* target = (const float*)d_in[3];
  const int*   matrix = (const int*)d_in[4];
  float* out = (float*)d_out;

  k_prep<<<LL + 8 + PP/256, 256, 0, stream>>>((const int4*)matrix, coor, target, prot, ptran);
  k_scan<<<1, 1024, 0, stream>>>();
  k_augfr<<<16, 256, 0, stream>>>(coor, target);
  dim3 grid(PP/(256*NP), (3*LL)/FPB);   // 3 x 384 = 1152 blocks (864 active)
  k_fape<<<grid, 256, 0, stream>>>(out);
}

// Round 15
// 34.706 us; speedup vs baseline: 2.2487x; 1.1964x over previous
//
#include <hip/hip_runtime.h>
#include <math.h>
#include <limits.h>

#define LL 2048
#define PP (LL*3)
#define FPB 16
#define NP 8

// -------- device-global scratch (rewritten every call) --------
__device__ int   g_firstj[LL];
__device__ int   g_cnt[LL];
__device__ int   g_ii[LL];
__device__ int   g_jj[LL];
__device__ int   g_K;
// folded frame records, 12 floats = 48 B: [M(9) | d(3)]; diff = p - M*t - d
// term0: frames [0, LL); term1: frames [LL, LL + LL + K)
__device__ __align__(16) float g_frames[(3*LL)*12];
// packed point records, 8 floats = 32 B: [p.xyz | t.xyz | pad pad]
__device__ __align__(16) float g_pts[PP*8];
__device__ double g_sum[2];

// rigid_from_3points for one residue: x = 9 floats (x1,x2,x3 rows)
__device__ inline void rigid3(const float* x, float* rot, float* tran) {
  float x1x=x[0],x1y=x[1],x1z=x[2];
  float x2x=x[3],x2y=x[4],x2z=x[5];
  float x3x=x[6],x3y=x[7],x3z=x[8];
  float v1x=x3x-x2x, v1y=x3y-x2y, v1z=x3z-x2z;
  float v2x=x1x-x2x, v2y=x1y-x2y, v2z=x1z-x2z;
  float n1 = sqrtf(v1x*v1x+v1y*v1y+v1z*v1z) + 0.001f;
  float e1x=v1x/n1, e1y=v1y/n1, e1z=v1z/n1;
  float dd = e1x*v2x+e1y*v2y+e1z*v2z;
  float u2x=v2x-e1x*dd, u2y=v2y-e1y*dd, u2z=v2z-e1z*dd;
  float n2 = sqrtf(u2x*u2x+u2y*u2y+u2z*u2z) + 1e-8f;
  float e2x=u2x/n2, e2y=u2y/n2, e2z=u2z/n2;
  rot[0]=e1x; rot[1]=e1y; rot[2]=e1z;
  rot[3]=e2x; rot[4]=e2y; rot[5]=e2z;
  rot[6]=e1y*e2z - e1z*e2y;
  rot[7]=e1z*e2x - e1x*e2z;
  rot[8]=e1x*e2y - e1y*e2x;
  tran[0]=x2x; tran[1]=x2y; tran[2]=x2z;
}

// folded record: M = A^T * B, d = tp - M*tt   (A=R_pred rows, B=R_true rows)
__device__ inline void packfr12(float* fr, const float* A, const float* tp,
                                const float* B, const float* tt) {
  float M[9];
  #pragma unroll
  for (int i = 0; i < 3; ++i)
    #pragma unroll
    for (int j = 0; j < 3; ++j)
      M[i*3+j] = A[0+i]*B[0+j] + A[3+i]*B[3+j] + A[6+i]*B[6+j];
  #pragma unroll
  for (int i = 0; i < 9; ++i) fr[i] = M[i];
  #pragma unroll
  for (int i = 0; i < 3; ++i)
    fr[9+i] = tp[i] - (M[i*3]*tt[0] + M[i*3+1]*tt[1] + M[i*3+2]*tt[2]);
}

// blocks [0,LL): per-row matrix scan (first j>i with m!=0)
// blocks [LL, LL+8): term0 folded frames
// blocks [LL+8, LL+8+24): packed point records
__global__ void __launch_bounds__(256) k_prep(const int4* __restrict__ m4,
                                              const float* __restrict__ coor,
                                              const float* __restrict__ target,
                                              const float* __restrict__ prot,
                                              const float* __restrict__ ptran) {
  int bid = blockIdx.x;
  int t = threadIdx.x;
  if (bid < LL) {
    int i = bid;                        // row
    const int4* row = m4 + (size_t)i*512;   // 2048 cols = 512 int4
    int4 a = row[2*t], b = row[2*t+1];
    int j0 = t*8;
    int best = INT_MAX;
    if (a.x && (j0   > i)) best = j0;
    if (a.y && (j0+1 > i)) best = min(best, j0+1);
    if (a.z && (j0+2 > i)) best = min(best, j0+2);
    if (a.w && (j0+3 > i)) best = min(best, j0+3);
    if (b.x && (j0+4 > i)) best = min(best, j0+4);
    if (b.y && (j0+5 > i)) best = min(best, j0+5);
    if (b.z && (j0+6 > i)) best = min(best, j0+6);
    if (b.w && (j0+7 > i)) best = min(best, j0+7);
    for (int o = 32; o >= 1; o >>= 1) best = min(best, __shfl_xor(best, o));
    __shared__ int wmin[4];
    int lane = t & 63, wid = t >> 6;
    if (lane == 0) wmin[wid] = best;
    __syncthreads();
    if (t == 0)
      g_firstj[i] = min(min(wmin[0], wmin[1]), min(wmin[2], wmin[3]));
  } else if (bid < LL + 8) {
    int f = (bid - LL)*256 + t;
    if (f == 0) { g_sum[0] = 0.0; g_sum[1] = 0.0; }
    if (f >= LL) return;
    float B[9], tt[3];
    rigid3(target + f*9, B, tt);
    float A[9], tp[3];
    #pragma unroll
    for (int i = 0; i < 9; ++i) A[i] = prot[f*9+i];
    #pragma unroll
    for (int i = 0; i < 3; ++i) tp[i] = ptran[f*3+i];
    packfr12(g_frames + f*12, A, tp, B, tt);
  } else {
    int p = (bid - LL - 8)*256 + t;     // p < 6144
    float4* o4 = reinterpret_cast<float4*>(g_pts);
    o4[p*2+0] = make_float4(coor[p*3], coor[p*3+1], coor[p*3+2], target[p*3]);
    o4[p*2+1] = make_float4(target[p*3+1], target[p*3+2], 0.f, 0.f);
  }
}

// single block: exclusive prefix-sum of "row has pair", build ii/jj, K
__global__ void __launch_bounds__(1024) k_scan() {
  int t = threadIdx.x;
  int r0 = 2*t, r1 = 2*t+1;
  int f0 = g_firstj[r0], f1 = g_firstj[r1];
  int h0 = (f0 != INT_MAX) ? 1 : 0;
  int h1 = (f1 != INT_MAX) ? 1 : 0;
  int local = h0 + h1;
  int lane = t & 63;
  int wid  = t >> 6;                 // 16 waves
  int incl = local;
  for (int o = 1; o < 64; o <<= 1) {
    int v = __shfl_up(incl, o);
    if (lane >= o) incl += v;
  }
  __shared__ int wsum[16];
  if (lane == 63) wsum[wid] = incl;
  __syncthreads();
  if (t < 16) {
    int iv = wsum[t];
    for (int o = 1; o < 16; o <<= 1) {
      int u = __shfl_up(iv, o);
      if (t >= o) iv += u;
    }
    wsum[t] = iv;
  }
  __syncthreads();
  int waveoff = (wid == 0) ? 0 : wsum[wid-1];
  int excl = waveoff + incl - local;   // pairs among rows < r0
  g_cnt[r0] = excl;
  g_cnt[r1] = excl + h0;
  if (h0) { g_ii[excl]      = r0; g_jj[excl]      = f0; }
  if (h1) { g_ii[excl + h0] = r1; g_jj[excl + h0] = f1; }
  if (t == 1023) g_K = waveoff + incl;
}

// term1 folded frame records computed directly from coords (no aug buffers)
__global__ void k_augfr(const float* __restrict__ coor,
                        const float* __restrict__ target) {
  int idx = blockIdx.x*blockDim.x + threadIdx.x;
  float xp[9], xt[9];
  int pos;
  if (idx < LL) {
    pos = idx + g_cnt[idx];
    #pragma unroll
    for (int c = 0; c < 9; ++c) { xp[c] = coor[idx*9+c]; xt[c] = target[idx*9+c]; }
  } else {
    int k = idx - LL;
    if (k >= g_K) return;
    int a = g_ii[k], b = g_jj[k];
    pos = a + k + 1;
    #pragma unroll
    for (int c = 0; c < 9; ++c) {
      xp[c] = 0.5f*(coor[a*9+c]   + coor[b*9+c]);
      xt[c] = 0.5f*(target[a*9+c] + target[b*9+c]);
    }
  }
  float A[9], tp[3], B[9], tt[3];
  rigid3(xp, A, tp);
  rigid3(xt, B, tt);
  packfr12(g_frames + (size_t)(LL + pos)*12, A, tp, B, tt);
}

// fused FAPE — EXACT R7 kernel (measured best: 34.7 us total): NP=8 points
// per thread in VGPRs, FPB=16 frames via wave-uniform global float4 loads
// (-> s_load, SGPRs), #pragma unroll 2, launch_bounds(256,4). NO fused
// finalize (R14 lesson: per-block threadfence+done-atomic tail costs ~5-7 us).
__global__ void __launch_bounds__(256, 4) k_fape() {
  int Ftot = 2*LL + g_K;
  int f0 = blockIdx.y * FPB;
  if (f0 >= Ftot) return;
  int nf = min(FPB, Ftot - f0);
  int term1 = (f0 >= LL) ? 1 : 0;
  float clampv = term1 ? 5.f : 40.f;
  int t = threadIdx.x;

  int pbase = blockIdx.x*(256*NP) + t;   // grid.x * 256 * NP == PP exactly
  const float4* pt4 = reinterpret_cast<const float4*>(g_pts);
  float px[NP], py[NP], pz[NP], ttx[NP], tty[NP], ttz[NP];
  #pragma unroll
  for (int k = 0; k < NP; ++k) {
    int p = pbase + k*256;
    float4 a = pt4[p*2+0];
    float4 b = pt4[p*2+1];
    px[k] = a.x; py[k] = a.y; pz[k] = a.z;
    ttx[k] = a.w; tty[k] = b.x; ttz[k] = b.y;
  }
  float acc = 0.f;

  // wave-uniform frame pointer: compiler promotes to scalar loads (SGPRs)
  const float4* fr4 = reinterpret_cast<const float4*>(g_frames) + (size_t)f0*3;
  #pragma unroll 2
  for (int q = 0; q < nf; ++q) {
    float4 w0 = fr4[q*3+0];   // M00 M01 M02 M10
    float4 w1 = fr4[q*3+1];   // M11 M12 M20 M21
    float4 w2 = fr4[q*3+2];   // M22 d0  d1  d2
    #pragma unroll
    for (int k = 0; k < NP; ++k) {
      float m0 = fmaf(w0.x, ttx[k], fmaf(w0.y, tty[k], fmaf(w0.z, ttz[k], w2.y)));
      float m1 = fmaf(w0.w, ttx[k], fmaf(w1.x, tty[k], fmaf(w1.y, ttz[k], w2.z)));
      float m2 = fmaf(w1.z, ttx[k], fmaf(w1.w, tty[k], fmaf(w2.x, ttz[k], w2.w)));
      float dx = px[k] - m0, dy = py[k] - m1, dz = pz[k] - m2;
      float ss = fmaf(dx, dx, fmaf(dy, dy, fmaf(dz, dz, 0.001f)));
      acc += fminf(__builtin_amdgcn_sqrtf(ss), clampv);
    }
  }

  for (int o = 32; o >= 1; o >>= 1) acc += __shfl_down(acc, o);
  __shared__ float w[4];
  int lane = t & 63, wid = t >> 6;
  if (lane == 0) w[wid] = acc;
  __syncthreads();
  if (t == 0) {
    double s = (double)w[0] + (double)w[1] + (double)w[2] + (double)w[3];
    atomicAdd(&g_sum[term1], s);
  }
}

__global__ void k_final(float* __restrict__ out) {
  int K = g_K;
  double fape = g_sum[0] / ((double)LL * (double)PP);
  double r;
  if (K == 0) {
    r = fape / 10.0;
  } else {
    double fp = g_sum[1] / ((double)(LL + K) * (double)PP);
    r = (fape + fp) / 10.0;
  }
  out[0] = (float)r;
}

extern "C" void kernel_launch(void* const* d_in, const int* in_sizes, int n_in,
                              void* d_out, int out_size, void* d_ws, size_t ws_size,
                              hipStream_t stream) {
  const float* coor   = (const float*)d_in[0];
  const float* prot   = (const float*)d_in[1];
  const float* ptran  = (const float*)d_in[2];
  const float* target = (const float*)d_in[3];
  const int*   matrix = (const int*)d_in[4];
  float* out = (float*)d_out;

  k_prep<<<LL + 8 + PP/256, 256, 0, stream>>>((const int4*)matrix, coor, target, prot, ptran);
  k_scan<<<1, 1024, 0, stream>>>();
  k_augfr<<<16, 256, 0, stream>>>(coor, target);
  dim3 grid(PP/(256*NP), (3*LL)/FPB);   // 3 x 384 = 1152 blocks (864 active)
  k_fape<<<grid, 256, 0, stream>>>();
  k_final<<<1, 1, 0, stream>>>(out);
}